// Round 1
// baseline (98.506 us; speedup 1.0000x reference)
//
#include <hip/hip_runtime.h>

// IrrepsIndexedLinear: y_ir[n,o,i] = alpha * sum_m x_ir[n,m,i] * w[seg(n), ir, m, o]
// N=2048, MUL=128, dims {1,3,5}, G=32, alpha = 1/64.
//
// Round-3 structure (round-2 measured 93.6us total; rocprof shows ~85us of
// that is two 256MiB harness poison fills at HBM roofline -> kernel-only
// ~8.6us vs a ~4-5us kernel roofline):
//  - uniform TR=8 rows per tile for ALL irreps -> each tr-group owns exactly
//    one row n (RP == D): no intra-thread row/i division, and last-tile
//    padding waste drops (avg 4 rows/group vs 16 for ir0's old TR=32).
//  - grid = 864 = 27*32; bid -> (irrep, tile) interleaved with period 27
//    (9 ir2 + 9 ir1 + 9 ir0): all blocks are co-resident, so per-CU cost mix
//    must be balanced by construction; heavy ir2 tiles first (LPT). Round 2's
//    544-block layout gave 32 CUs a 3rd block (up to ~1.4x tail).
//  - repeats[] prefetched into registers (unrolled, uniform -> scalar loads)
//    before the tile scan: no serial dependent-load chain in the scan.
//  - epilogue: thread's 4 o's x D i's are 4D CONTIGUOUS floats -> D float4
//    stores (round 2 did 4*RP strided b32 stores).
//  - K loop unchanged in spirit: 1 global b128 (W, streamed, L1/L2-hot,
//    8x reuse inside the block) + D LDS b32 broadcasts (adjacent i's merge)
//    + 4D FMA per m; zero barriers after the single staging syncthreads.
//    Accumulation order per output is identical to round 2 (absmax stays 0).

#define NGROUP 32
#define WSTRIDE (128 * 128 * 3) // floats per weight group
#define ALPHA 0.015625f         // 1/sqrt(32*128) = 1/64 exactly

#define TR 8            // rows (elements n) per tile, all irreps
#define PER 27          // 9 ir2 + 9 ir1 + 9 ir0 per period
#define GRID_BLOCKS 864 // PER * 32 ; per-irrep tile cap = 32 + 2048/TR = 288 = 9*32
#define LDS_FLOATS 5120 // TR*128*5 (ir2) = 20 KB

template <int D>
__device__ inline void run_ir(int lt, const float* __restrict__ x,
                              const float* __restrict__ w_base_ir, // w + ir off
                              const int* __restrict__ repeats,
                              float* __restrict__ obase, // out + ir out offset
                              float* __restrict__ Xs) {
  // ---- prefetch counts (uniform address -> scalar loads, all in flight) ----
  int cnt[NGROUP];
#pragma unroll
  for (int gg = 0; gg < NGROUP; ++gg) cnt[gg] = repeats[gg];

  // ---- group-aligned tile lookup (uniform across block, branch-free) ----
  int off = 0, g = -1, row0 = 0, nr = 0, tacc = 0;
#pragma unroll
  for (int gg = 0; gg < NGROUP; ++gg) {
    int c = cnt[gg];
    int tg = (c + TR - 1) >> 3;
    if (g < 0 && lt < tacc + tg) {
      int tig = lt - tacc;
      g = gg;
      row0 = off + tig * TR;
      nr = min(TR, c - tig * TR);
    }
    tacc += tg;
    off += c;
  }
  if (g < 0) return; // beyond real tile count for this irrep (whole block)

  const int tid = threadIdx.x;
  const int to = tid & 31; // owns out columns o = to*4 .. to*4+3
  const int tr = tid >> 5; // owns row n = row0 + tr (one row, all D i's)

  constexpr int ROWELEMS = 128 * D;
  constexpr int BMELEMS = TR * ROWELEMS;

  // ---- stage X tile raw into LDS (straight float4 copy; zero-fill > nr) ----
  {
    const float4* xsrc = (const float4*)(x + (size_t)row0 * ROWELEMS);
    float4* xdst = (float4*)Xs;
    const int limit4 = nr * (ROWELEMS / 4);
    constexpr int Q = BMELEMS / 4; // 256 / 768 / 1280 -> multiple of 256
    const float4 z = make_float4(0.f, 0.f, 0.f, 0.f);
#pragma unroll
    for (int q = tid; q < Q; q += 256) xdst[q] = (q < limit4) ? xsrc[q] : z;
  }
  __syncthreads();

  const float* w_g = w_base_ir + (size_t)g * WSTRIDE;
  const float4* wp = (const float4*)w_g + to; // stride per m: 32 float4s
  const float* xrow = Xs + tr * ROWELEMS;

  float acc[D][4];
#pragma unroll
  for (int i = 0; i < D; ++i)
#pragma unroll
    for (int oj = 0; oj < 4; ++oj) acc[i][oj] = 0.0f;

  // ---- K loop: no barriers; W streamed from global, X broadcast from LDS --
#pragma unroll 8
  for (int m = 0; m < 128; ++m) {
    const float4 wf = wp[m * 32];
    float xs[D];
#pragma unroll
    for (int i = 0; i < D; ++i) xs[i] = xrow[m * D + i];
#pragma unroll
    for (int i = 0; i < D; ++i) {
      acc[i][0] += xs[i] * wf.x;
      acc[i][1] += xs[i] * wf.y;
      acc[i][2] += xs[i] * wf.z;
      acc[i][3] += xs[i] * wf.w;
    }
  }

  // ---- epilogue: y[n, o, i]; thread's 4D outputs are contiguous ----
  if (tr < nr) {
    float* orow = obase + (size_t)(row0 + tr) * ROWELEMS + to * (4 * D);
    float vals[4 * D];
#pragma unroll
    for (int oj = 0; oj < 4; ++oj)
#pragma unroll
      for (int i = 0; i < D; ++i) vals[oj * D + i] = acc[i][oj] * ALPHA;
    float4* o4 = (float4*)orow;
#pragma unroll
    for (int q = 0; q < D; ++q)
      o4[q] = make_float4(vals[4 * q + 0], vals[4 * q + 1], vals[4 * q + 2],
                          vals[4 * q + 3]);
  }
}

__global__ __launch_bounds__(256) void IrrepsIndexedLinear_39161511805249_kernel(
    const float* __restrict__ x0, const float* __restrict__ x1,
    const float* __restrict__ x2, const float* __restrict__ w,
    const int* __restrict__ repeats, float* __restrict__ out) {
  __shared__ float Xs[LDS_FLOATS]; // 20 KB

  const int bid = blockIdx.x;
  const int j = bid / PER;       // 0..31
  const int k = bid - j * PER;   // 0..26 ; ir2 first (LPT), then ir1, ir0
  if (k < 9) {
    // ir2: d=5 ; w offset 32768 ; out offset 2048*128*4
    run_ir<5>(j * 9 + k, x2, w + 32768, repeats, out + 1048576, Xs);
  } else if (k < 18) {
    // ir1: d=3 ; w offset 16384 ; out offset 2048*128
    run_ir<3>(j * 9 + (k - 9), x1, w + 16384, repeats, out + 262144, Xs);
  } else {
    // ir0: d=1 ; w offset 0 ; out offset 0
    run_ir<1>(j * 9 + (k - 18), x0, w, repeats, out, Xs);
  }
}

extern "C" void kernel_launch(void* const* d_in, const int* in_sizes, int n_in,
                              void* d_out, int out_size, void* d_ws, size_t ws_size,
                              hipStream_t stream) {
  const float* x0 = (const float*)d_in[0];
  const float* x1 = (const float*)d_in[1];
  const float* x2 = (const float*)d_in[2];
  const float* w = (const float*)d_in[3];
  const int* repeats = (const int*)d_in[4];
  float* out = (float*)d_out;

  IrrepsIndexedLinear_39161511805249_kernel<<<GRID_BLOCKS, 256, 0, stream>>>(
      x0, x1, x2, w, repeats, out);
}